// Round 9
// baseline (133.535 us; speedup 1.0000x reference)
//
#include <hip/hip_runtime.h>

// Problem constants (from reference)
#define T_TREES 200
#define BATCH   2048
#define D_FEAT  512
#define N_NODE  64
#define LR      0.01f

typedef __attribute__((__ext_vector_type__(8)))  __bf16 bf16x8;
typedef __attribute__((__ext_vector_type__(16))) float  f32x16;

__device__ __forceinline__ unsigned short f32_to_bf16(float f) {
    unsigned u = __float_as_uint(f);
    u += 0x7FFFu + ((u >> 16) & 1u);   // RNE
    return (unsigned short)(u >> 16);
}

__device__ __forceinline__ void gload_lds16(const void* g, void* l) {
    __builtin_amdgcn_global_load_lds(
        (__attribute__((address_space(1))) void*)(void*)g,
        (__attribute__((address_space(3))) void*)l,
        16, 0, 0);
}

// ---------------- fused prep kernel ----------------
// kg-major layouts so main-kernel access is contiguous:
// x_p[mt 16][kg 64][m 128][8k] bf16 ; w_p[pair 100][kg 64][n' 128][8k] bf16 ;
// w_dt[t 200][32 node][64 n] bf16.
// Grid 3456: [0,256) prep_x | [256,1856) prep_wt | [1856,3456) prep_wd.
__global__ __launch_bounds__(256) void prep_all(
    const float* __restrict__ x, const float* __restrict__ w_t,
    const float* __restrict__ w_d,
    unsigned short* __restrict__ x_p, unsigned short* __restrict__ w_p,
    unsigned short* __restrict__ w_dt) {
    __shared__ float tile[64 * 65];
    int b = blockIdx.x;
    if (b < 256) {
        // ---- x [2048][512] f32 -> x_p ----
        int mb = b >> 3, slab = b & 7;
        const float* src = x + (mb * 64) * D_FEAT + slab * 64;
        #pragma unroll
        for (int p = 0; p < 16; ++p) {
            int idx = p * 256 + threadIdx.x;
            int r = idx >> 6, c = idx & 63;
            tile[r * 65 + c] = src[r * D_FEAT + c];
        }
        __syncthreads();
        int mt = mb >> 1, mq = mb & 1;
        unsigned short* dst = x_p + mt * 65536 + slab * 8192 + mq * 512;
        #pragma unroll
        for (int p = 0; p < 8; ++p) {
            int idx = p * 256 + threadIdx.x;
            int kgl = idx >> 8;
            int r   = (idx >> 2) & 63;
            int jp  = idx & 3;
            ushort2 o;
            o.x = f32_to_bf16(tile[r * 65 + kgl * 8 + jp * 2]);
            o.y = f32_to_bf16(tile[r * 65 + kgl * 8 + jp * 2 + 1]);
            *(ushort2*)(dst + kgl * 1024 + r * 8 + jp * 2) = o;
        }
    } else if (b < 1856) {
        // ---- w_t [t][d][n] f32 -> w_p (pair-interleaved, kg-major) ----
        int bb = b - 256;
        int t = bb >> 3, slab = bb & 7;
        const float* src = w_t + t * (D_FEAT * N_NODE) + slab * 64 * N_NODE;
        #pragma unroll
        for (int p = 0; p < 16; ++p) {
            int idx = p * 256 + threadIdx.x;
            int d = idx >> 6, n = idx & 63;
            tile[d * 65 + n] = src[d * N_NODE + n];
        }
        __syncthreads();
        unsigned short* dst = w_p + (t >> 1) * 65536 + slab * 8192 + (t & 1) * 512;
        #pragma unroll
        for (int p = 0; p < 8; ++p) {
            int idx = p * 256 + threadIdx.x;
            int kgl = idx >> 8;
            int n   = (idx >> 2) & 63;
            int jp  = idx & 3;
            ushort2 o;
            o.x = f32_to_bf16(tile[(kgl * 8 + jp * 2) * 65 + n]);
            o.y = f32_to_bf16(tile[(kgl * 8 + jp * 2 + 1) * 65 + n]);
            *(ushort2*)(dst + kgl * 1024 + n * 8 + jp * 2) = o;
        }
    } else {
        // ---- w_d [t][n][15] f32 -> w_dt [t][32][64] (rows 15..31 zero) ----
        int i = (b - 1856) * 256 + threadIdx.x;          // 409600 = 200*32*64
        int n = i & 63;
        int l = (i >> 6) & 31;
        int t = i >> 11;
        float v = (l < 15) ? w_d[(t * 64 + n) * 15 + l] : 0.f;
        w_dt[i] = f32_to_bf16(v);
    }
}

// ---------------- main fused kernel ----------------
// Block = 2 trees (N=128) x 128 batch rows, 256 threads (4 waves).
// Wave tile 64x64 (wm = w>>1 row-half, wn = w&1 = tree).
// K-loop: 8 chunks of BK=64 (halves barrier-drain units vs R8's 16 — the
// invariant that pinned R2/R6/R7/R8 at 44-51 us). 32 MFMA/wave per barrier
// (~350 cyc compute) covers the L2-latency drain (~200 cyc).
// A (x) frags REGISTER-DIRECT from kg-major x_p (16B/lane contiguous, 512B/wave
// runs, L2-resident), prefetched one full chunk ahead (8+8 frags).
// B via LDS double-buffer (2x16KB). Phase-staggered K start ((c+phase)&7)
// decorrelates same-pair/same-mt blocks' L2 line demand + barrier alignment.
// ~150 unified regs -> __launch_bounds__(256,3): 3 blocks/CU, no spill.
__global__ __launch_bounds__(256, 3) void gbdt_main(
    const unsigned short* __restrict__ x_p,    // [16][64][128][8] bf16
    const unsigned short* __restrict__ w_p,    // [100][64][128][8] bf16
    const unsigned short* __restrict__ w_dt,   // [200][32][64] bf16
    const float* __restrict__ b_t,             // [200][64]
    const float* __restrict__ b_d,             // [200][15]
    const float* __restrict__ w_l,             // [200][16]
    const float* __restrict__ b_l,             // [200]
    float* __restrict__ f_ws)                  // [2048][200]  (b-major)
{
    // B dbuf: [0,32768) (16 KB per buffer). Overlays after GEMM1:
    // H [0,34816) = [2 tree][128 m][68 col] bf16 ; P [0,17408) = [2][128][17] f32.
    __shared__ alignas(16) char smem[34816];
    unsigned short* Hs = (unsigned short*)smem;
    float*          Pf = (float*)smem;

    const int tid    = threadIdx.x;
    const int lane   = tid & 63;
    const int w      = tid >> 6;
    const int lane31 = lane & 31;
    const int kh     = lane >> 5;
    const int wm     = w >> 1;       // row-half (0/1)
    const int wn     = w & 1;        // tree-in-pair (0/1)

    const int xcd  = blockIdx.x & 7;
    const int slot = blockIdx.x >> 3;     // 0..207
    const int mt   = slot & 15;           // 128-row tile
    const int pj   = slot >> 4;           // 0..12
    const int pair = xcd * 13 + pj;
    if (pair >= 100) return;
    const int t0 = pair * 2;
    const int m0 = mt * 128;
    const int phase = slot & 7;           // K-start stagger

    // A frag base (elems): frag(cc,s2,mb) = pA + cc*8192 + s2*2048 + mb*256
    const unsigned short* pA = x_p + mt * 65536 + kh * 1024 + (wm * 64 + lane31) * 8;
    // B staging source (bytes): chunk cc at gb + cc*16384, 4 issues of 4096
    const char* gb = (const char*)(w_p + pair * 65536) + tid * 16;

    f32x16 acc[2][2];
    #pragma unroll
    for (int mb = 0; mb < 2; ++mb)
        #pragma unroll
        for (int nb = 0; nb < 2; ++nb)
            acc[mb][nb] = (f32x16)(0.f);

    // preload chunk 0 (logical) A frags + stage B chunk 0 into buf 0
    bf16x8 a_cur[8], a_nxt[8];
    {
        const unsigned short* pc = pA + phase * 8192;
        #pragma unroll
        for (int s2 = 0; s2 < 4; ++s2)
            #pragma unroll
            for (int mb = 0; mb < 2; ++mb)
                a_cur[s2 * 2 + mb] = *(const bf16x8*)(pc + s2 * 2048 + mb * 256);
        #pragma unroll
        for (int i = 0; i < 4; ++i)
            gload_lds16(gb + phase * 16384 + i * 4096, smem + tid * 16 + i * 4096);
    }

    // ---- K loop: 8 chunks of 64, B dbuf, A reg ping-pong, staggered ----
    #pragma unroll
    for (int c = 0; c < 8; ++c) {
        __syncthreads();                             // drains stage(c)+A(c) loads
        if (c < 7) {
            const int cc = (c + 1 + phase) & 7;      // logical chunk index
            char* nx = smem + ((c + 1) & 1) * 16384;
            #pragma unroll
            for (int i = 0; i < 4; ++i)
                gload_lds16(gb + cc * 16384 + i * 4096, nx + tid * 16 + i * 4096);
            const unsigned short* pc = pA + cc * 8192;
            #pragma unroll
            for (int s2 = 0; s2 < 4; ++s2)
                #pragma unroll
                for (int mb = 0; mb < 2; ++mb)
                    a_nxt[s2 * 2 + mb] = *(const bf16x8*)(pc + s2 * 2048 + mb * 256);
        }
        const char* buf = smem + (c & 1) * 16384;
        #pragma unroll
        for (int s2 = 0; s2 < 4; ++s2) {
            const int kgl = 2 * s2 + kh;
            bf16x8 bv[2];
            #pragma unroll
            for (int nb = 0; nb < 2; ++nb)
                bv[nb] = *(const bf16x8*)(buf + (kgl * 128 + wn * 64 + nb * 32 + lane31) * 16);
            #pragma unroll
            for (int mb = 0; mb < 2; ++mb)
                #pragma unroll
                for (int nb = 0; nb < 2; ++nb)
                    acc[mb][nb] = __builtin_amdgcn_mfma_f32_32x32x16_bf16(
                        a_cur[s2 * 2 + mb], bv[nb], acc[mb][nb], 0, 0, 0);
        }
        #pragma unroll
        for (int i = 0; i < 8; ++i) a_cur[i] = a_nxt[i];
    }

    __syncthreads();                                 // last B frag reads done

    // ---- epilogue: h = relu(acc + b_t) -> H LDS; acc dies here ----
    // C/D layout (32x32): col = lane&31, row = (r&3) + 8*(r>>2) + 4*(lane>>5)
    #pragma unroll
    for (int nb = 0; nb < 2; ++nb) {
        float btv = b_t[(t0 + wn) * 64 + nb * 32 + lane31];
        #pragma unroll
        for (int mb = 0; mb < 2; ++mb)
            #pragma unroll
            for (int r = 0; r < 16; ++r) {
                int m = wm * 64 + mb * 32 + (r & 3) + 8 * (r >> 2) + 4 * kh;
                float h = fmaxf(acc[mb][nb][r] + btv, 0.f);
                Hs[wn * 8704 + m * 68 + nb * 32 + lane31] = f32_to_bf16(h);
            }
    }
    __syncthreads();                                 // H complete for both trees

    // ---- GEMM2: wave (wm,wn): logit[64 m x 16 l] for tree wn, K=64 ----
    f32x16 acc2[2] = { (f32x16)(0.f), (f32x16)(0.f) };
    const unsigned short* pW = w_dt + (t0 + wn) * 2048 + lane31 * 64 + kh * 8;
    #pragma unroll
    for (int s = 0; s < 4; ++s) {
        bf16x8 bv = *(const bf16x8*)(pW + s * 16);
        #pragma unroll
        for (int i = 0; i < 2; ++i) {
            const unsigned short* pH =
                Hs + wn * 8704 + (wm * 64 + i * 32 + lane31) * 68 + s * 16 + kh * 8;
            bf16x8 av = *(const bf16x8*)pH;
            acc2[i] = __builtin_amdgcn_mfma_f32_32x32x16_bf16(av, bv, acc2[i], 0, 0, 0);
        }
    }
    __syncthreads();                                 // H reads done (P overlays H)

    // ---- p = sigmoid(logit + b_d) -> P [2][128][17] f32 ----
    if (lane31 < 15) {
        float bdv = b_d[(t0 + wn) * 15 + lane31];
        #pragma unroll
        for (int i = 0; i < 2; ++i)
            #pragma unroll
            for (int r = 0; r < 16; ++r) {
                int m = wm * 64 + i * 32 + (r & 3) + 8 * (r >> 2) + 4 * kh;
                float lg = acc2[i][r] + bdv;
                Pf[(wn * 128 + m) * 17 + lane31] = 1.f / (1.f + __expf(-lg));
            }
    }
    __syncthreads();

    // ---- soft routing + leaf score: thread = (tree j, row m) ----
    {
        int m = tid & 127;
        int j = tid >> 7;
        int t = t0 + j;
        float pv[15];
        #pragma unroll
        for (int i = 0; i < 15; ++i) pv[i] = Pf[(j * 128 + m) * 17 + i];
        float facc = 0.f;
        #pragma unroll
        for (int leaf = 0; leaf < 16; ++leaf) {
            float mu = 1.f;
            int node = 0;
            #pragma unroll
            for (int d = 0; d < 4; ++d) {
                int bit = (leaf >> (3 - d)) & 1;
                float p = pv[node];
                mu *= bit ? (1.f - p) : p;
                node = 2 * node + 1 + bit;
            }
            facc += mu * w_l[t * 16 + leaf];
        }
        f_ws[(m0 + m) * T_TREES + t] = tanhf(facc + b_l[t]);   // b-major
    }
}

// ---------------- boosting prefix-sum ----------------
// f_ws is [B][T] -> coalesced read.
__global__ void scan_k(const float* __restrict__ f_ws, const float* __restrict__ f0p,
                       float* __restrict__ out) {
    int b = blockIdx.x, tid = threadIdx.x;
    int lane = tid & 63, wid = tid >> 6;
    float f0 = f0p[0];
    float x = (tid < T_TREES) ? f_ws[b * T_TREES + tid] : 0.f;
    #pragma unroll
    for (int off = 1; off < 64; off <<= 1) {
        float y = __shfl_up(x, off, 64);
        if (lane >= off) x += y;
    }
    __shared__ float wsum[4];
    if (lane == 63) wsum[wid] = x;
    __syncthreads();
    float base = 0.f;
    for (int i = 0; i < wid; ++i) base += wsum[i];
    float incl = x + base;
    if (tid == 0) out[b * (T_TREES + 1)] = f0;
    if (tid < T_TREES) out[b * (T_TREES + 1) + 1 + tid] = f0 + LR * incl;
}

extern "C" void kernel_launch(void* const* d_in, const int* in_sizes, int n_in,
                              void* d_out, int out_size, void* d_ws, size_t ws_size,
                              hipStream_t stream) {
    const float* x   = (const float*)d_in[0];
    const float* w_t = (const float*)d_in[2];
    const float* b_t = (const float*)d_in[3];
    const float* w_d = (const float*)d_in[4];
    const float* b_d = (const float*)d_in[5];
    const float* w_l = (const float*)d_in[6];
    const float* b_l = (const float*)d_in[7];
    const float* f_0 = (const float*)d_in[8];
    float* out = (float*)d_out;

    char* ws = (char*)d_ws;
    unsigned short* x_p  = (unsigned short*)(ws);               // 2,097,152 B
    unsigned short* w_p  = (unsigned short*)(ws + 2097152);     // 13,107,200 B
    unsigned short* w_dt = (unsigned short*)(ws + 15204352);    //   819,200 B
    float*          f_ws = (float*)(ws + 16023552);             // 1,638,400 B

    prep_all<<<3456, 256, 0, stream>>>(x, w_t, w_d, x_p, w_p, w_dt);
    gbdt_main<<<1664, 256, 0, stream>>>(x_p, w_p, w_dt, b_t, b_d, w_l, b_l, f_ws);
    scan_k<<<BATCH, 256, 0, stream>>>(f_ws, f_0, out);
}